// Round 1
// baseline (419.222 us; speedup 1.0000x reference)
//
#include <hip/hip_runtime.h>

typedef float f32x4 __attribute__((ext_vector_type(4)));
typedef short s16x8 __attribute__((ext_vector_type(8)));
typedef short s16x4 __attribute__((ext_vector_type(4)));

#define NLAB 10
#define LEGO 128
#define INA  128
#define OUTC 512
#define KDIM 1152               // 9 offsets * 128 ic
#define WPITCH 34
#define XL_ELEMS (6*34*128)     // 26112 bf16 = 52224 B

__device__ __forceinline__ unsigned short f2bf(float f) {
    unsigned u = __builtin_bit_cast(unsigned, f);
    u += 0x7fffu + ((u >> 16) & 1u);          // round-to-nearest-even
    return (unsigned short)(u >> 16);
}
__device__ __forceinline__ float bf2f(unsigned short h) {
    return __builtin_bit_cast(float, ((unsigned)h) << 16);
}

// Wt[lab][l][off*128+ic] = bf16(ff[lab][l][ic][off])
__global__ void k_prep_w(const float* __restrict__ ff, unsigned short* __restrict__ wt) {
    int t = blockIdx.x * 256 + threadIdx.x;
    if (t >= NLAB * LEGO * INA) return;
    int ic = t & 127;
    int ll = t >> 7;                           // lab*128 + l
    const float* src = ff + (size_t)(ll * 128 + ic) * 9;
    unsigned short* dst = wt + (size_t)ll * KDIM + ic;
#pragma unroll
    for (int off = 0; off < 9; ++off) dst[off * 128] = f2bf(src[off]);
}

// sel[o] = argmax_l comb0[o,l] (first max), c[o] = coeff0[o, sel[o]]
__global__ void k_prep_sel(const float* __restrict__ coeff, const float* __restrict__ comb,
                           int* __restrict__ sel, float* __restrict__ cs) {
    int o = blockIdx.x * 256 + threadIdx.x;
    if (o >= OUTC) return;
    const float* row = comb + (size_t)o * LEGO;
    float best = row[0]; int bi = 0;
    for (int l = 1; l < LEGO; ++l) { float v = row[l]; if (v > best) { best = v; bi = l; } }
    sel[o] = bi;
    cs[o] = coeff[(size_t)o * LEGO + bi];
}

__global__ __launch_bounds__(256) void k_conv(
    const float* __restrict__ x, const int* __restrict__ label,
    const unsigned short* __restrict__ wt,
    const int* __restrict__ sel, const float* __restrict__ cs,
    float* __restrict__ out)
{
    __shared__ unsigned short xl[XL_ELEMS];   // staged x (swizzled); later aliased as feat bf16 [128][132]
    __shared__ int   sel_s[OUTC];
    __shared__ float c_s[OUTC];

    const int t  = threadIdx.x;
    const int b  = blockIdx.y;
    const int nt = blockIdx.x;                // 0..7 -> pixel rows h0..h0+3
    const int h0 = nt * 4;

    for (int i = t; i < OUTC; i += 256) { sel_s[i] = sel[i]; c_s[i] = cs[i]; }

    {   // zero x tile (halo rows / border cols rely on this)
        uint4* z = (uint4*)xl;
        for (int i = t; i < XL_ELEMS/8; i += 256) z[i] = make_uint4(0u,0u,0u,0u);
    }
    __syncthreads();

    const int lab = label[b];

    // stage interior: rows h0-1..h0+4, layout [row][w1][ic] with 16B XOR swizzle on ic-chunk
    for (int i = t; i < 6144; i += 256) {
        int wq  = i & 7;
        int ri  = i >> 3;                     // ic*6 + row
        int row = ri % 6;
        int ic  = ri / 6;
        int h = h0 - 1 + row;
        if (h >= 0 && h < 32) {
            const f32x4 v = *(const f32x4*)(x + (((size_t)b * INA + ic) << 10) + h * 32 + wq * 4);
            int icl = ic & 7, ich = ic >> 3;
#pragma unroll
            for (int j = 0; j < 4; ++j) {
                int w1 = wq * 4 + j + 1;      // 1..32 (cols 0,33 stay zero)
                int el = (row * WPITCH + w1) * 128 + (((ich ^ (w1 & 15)) << 3) | icl);
                xl[el] = f2bf(v[j]);
            }
        }
    }
    __syncthreads();

    const int lane = t & 63;
    const int wv   = t >> 6;
    const int l16  = lane & 15;
    const int quad = lane >> 4;
    const int m_base = (wv & 1) << 6;
    const int n_base = (wv >> 1) << 6;

    const unsigned short* wl = wt + (size_t)lab * (LEGO * KDIM);
    const unsigned short* arow[4];
#pragma unroll
    for (int mi = 0; mi < 4; ++mi)
        arow[mi] = wl + (size_t)(m_base + mi*16 + l16) * KDIM + quad * 8;

    int prow[4], pcol[4];
#pragma unroll
    for (int ni = 0; ni < 4; ++ni) {
        int p = n_base + ni*16 + l16;
        prow[ni] = p >> 5;
        pcol[ni] = p & 31;
    }

    f32x4 acc[4][4];
    {
        f32x4 zz = {0.f, 0.f, 0.f, 0.f};
#pragma unroll
        for (int mi = 0; mi < 4; ++mi)
#pragma unroll
            for (int ni = 0; ni < 4; ++ni) acc[mi][ni] = zz;
    }

    for (int off = 0; off < 9; ++off) {
        const int dh = off / 3 - 1;
        const int dw = off % 3 - 1;
        int bbase[4], bsw[4];
#pragma unroll
        for (int ni = 0; ni < 4; ++ni) {
            int row = prow[ni] + dh + 1;      // 0..5, always staged
            int w1  = pcol[ni] + dw + 1;      // 0..33, borders are zeros
            bbase[ni] = (row * WPITCH + w1) * 128;
            bsw[ni]   = w1 & 15;
        }
#pragma unroll
        for (int kc = 0; kc < 4; ++kc) {
            const int kb = off * 128 + kc * 32;
            s16x8 a[4], bb[4];
#pragma unroll
            for (int mi = 0; mi < 4; ++mi)
                a[mi] = *(const s16x8*)(arow[mi] + kb);     // global, L2-hot (10 labels)
            const int jj = kc * 4 + quad;
#pragma unroll
            for (int ni = 0; ni < 4; ++ni)
                bb[ni] = *(const s16x8*)(xl + bbase[ni] + ((jj ^ bsw[ni]) << 3)); // ds_read_b128
#pragma unroll
            for (int mi = 0; mi < 4; ++mi)
#pragma unroll
                for (int ni = 0; ni < 4; ++ni)
                    acc[mi][ni] = __builtin_amdgcn_mfma_f32_16x16x32_bf16(a[mi], bb[ni], acc[mi][ni], 0, 0, 0);
        }
    }

    __syncthreads();                          // all LDS x reads done; reuse as feat
    unsigned short* featb = xl;               // feat bf16 [128][132] (pad breaks quad collisions)
#pragma unroll
    for (int mi = 0; mi < 4; ++mi)
#pragma unroll
        for (int ni = 0; ni < 4; ++ni) {
            int n = n_base + ni*16 + l16;
#pragma unroll
            for (int r = 0; r < 4; ++r) {
                int m = m_base + mi*16 + quad*4 + r;   // m89-verified C/D layout
                featb[m * 132 + n] = f2bf(acc[mi][ni][r]);
            }
        }
    __syncthreads();

    // out[b][o][nt*128 + p] = c[o] * feat[sel[o]][p]
    const size_t obase = ((size_t)b * OUTC) * 1024 + (size_t)nt * 128;
    for (int i = t; i < OUTC * 32; i += 256) {
        int pg = i & 31;
        int o  = i >> 5;
        s16x4 fv = *(const s16x4*)(featb + sel_s[o] * 132 + pg * 4);
        float cc = c_s[o];
        f32x4 ov;
#pragma unroll
        for (int j = 0; j < 4; ++j)
            ov[j] = cc * bf2f((unsigned short)fv[j]);
        *(f32x4*)(out + obase + (size_t)o * 1024 + pg * 4) = ov;
    }
}

extern "C" void kernel_launch(void* const* d_in, const int* in_sizes, int n_in,
                              void* d_out, int out_size, void* d_ws, size_t ws_size,
                              hipStream_t stream) {
    const float* x     = (const float*)d_in[0];
    const int*   label = (const int*)d_in[1];
    const float* ff    = (const float*)d_in[2];
    const float* coeff = (const float*)d_in[3];   // second_filter_coefficients (use [0] slice)
    const float* comb  = (const float*)d_in[4];   // second_filter_combination  (use [0] slice)
    float* out = (float*)d_out;

    char* ws = (char*)d_ws;
    unsigned short* wt = (unsigned short*)ws;               // 10*128*1152*2 = 2,949,120 B
    int*   sel = (int*)(ws + 2949120);                      // 2 KB
    float* cs  = (float*)(ws + 2949120 + 2048);             // 2 KB

    k_prep_w  <<<640, 256, 0, stream>>>(ff, wt);
    k_prep_sel<<<2,   256, 0, stream>>>(coeff, comb, sel, cs);
    k_conv    <<<dim3(8, 128), 256, 0, stream>>>(x, label, wt, sel, cs, out);
}

// Round 2
// 407.018 us; speedup vs baseline: 1.0300x; 1.0300x over previous
//
#include <hip/hip_runtime.h>

typedef float f32x4 __attribute__((ext_vector_type(4)));
typedef short s16x8 __attribute__((ext_vector_type(8)));
typedef short s16x4 __attribute__((ext_vector_type(4)));

#define NLAB 10
#define LEGO 128
#define INA  128
#define OUTC 512
#define KDIM 1152               // 9 offsets * 128 ic
#define WPITCH 34
#define XL_ELEMS (6*34*128)     // 26112 bf16 = 52224 B

__device__ __forceinline__ unsigned short f2bf(float f) {
    unsigned u = __builtin_bit_cast(unsigned, f);
    u += 0x7fffu + ((u >> 16) & 1u);          // round-to-nearest-even
    return (unsigned short)(u >> 16);
}
__device__ __forceinline__ float bf2f(unsigned short h) {
    return __builtin_bit_cast(float, ((unsigned)h) << 16);
}

// Wt[lab][l][off*128+ic] = bf16(ff[lab][l][ic][off])
__global__ void k_prep_w(const float* __restrict__ ff, unsigned short* __restrict__ wt) {
    int t = blockIdx.x * 256 + threadIdx.x;
    if (t >= NLAB * LEGO * INA) return;
    int ic = t & 127;
    int ll = t >> 7;                           // lab*128 + l
    const float* src = ff + (size_t)(ll * 128 + ic) * 9;
    unsigned short* dst = wt + (size_t)ll * KDIM + ic;
#pragma unroll
    for (int off = 0; off < 9; ++off) dst[off * 128] = f2bf(src[off]);
}

// sel[o] = argmax_l comb0[o,l] (first max), c[o] = coeff0[o, sel[o]]
__global__ void k_prep_sel(const float* __restrict__ coeff, const float* __restrict__ comb,
                           int* __restrict__ sel, float* __restrict__ cs) {
    int o = blockIdx.x * 256 + threadIdx.x;
    if (o >= OUTC) return;
    const float* row = comb + (size_t)o * LEGO;
    float best = row[0]; int bi = 0;
    for (int l = 1; l < LEGO; ++l) { float v = row[l]; if (v > best) { best = v; bi = l; } }
    sel[o] = bi;
    cs[o] = coeff[(size_t)o * LEGO + bi];
}

__global__ __launch_bounds__(256, 2) void k_conv(
    const float* __restrict__ x, const int* __restrict__ label,
    const unsigned short* __restrict__ wt,
    const int* __restrict__ sel, const float* __restrict__ cs,
    float* __restrict__ out)
{
    __shared__ unsigned short xl[XL_ELEMS];   // staged x (swizzled); later aliased as feat bf16 [128][132]

    const int t  = threadIdx.x;
    const int b  = blockIdx.y;
    const int nt = blockIdx.x;                // 0..7 -> pixel rows h0..h0+3
    const int h0 = nt * 4;

    {   // zero x tile (halo rows / border cols rely on this)
        uint4* z = (uint4*)xl;
        for (int i = t; i < XL_ELEMS/8; i += 256) z[i] = make_uint4(0u,0u,0u,0u);
    }
    __syncthreads();

    const int lab = label[b];

    // stage interior: rows h0-1..h0+4, layout [row][w1][ic] with 16B XOR swizzle on ic-chunk
    for (int i = t; i < 6144; i += 256) {
        int wq  = i & 7;
        int ri  = i >> 3;                     // ic*6 + row
        int row = ri % 6;
        int ic  = ri / 6;
        int h = h0 - 1 + row;
        if (h >= 0 && h < 32) {
            const f32x4 v = *(const f32x4*)(x + (((size_t)b * INA + ic) << 10) + h * 32 + wq * 4);
            int icl = ic & 7, ich = ic >> 3;
#pragma unroll
            for (int j = 0; j < 4; ++j) {
                int w1 = wq * 4 + j + 1;      // 1..32 (cols 0,33 stay zero)
                int el = (row * WPITCH + w1) * 128 + (((ich ^ (w1 & 15)) << 3) | icl);
                xl[el] = f2bf(v[j]);
            }
        }
    }
    __syncthreads();

    const int lane = t & 63;
    const int wv   = t >> 6;
    const int l16  = lane & 15;
    const int quad = lane >> 4;
    const int m_base = (wv & 1) << 6;
    const int n_base = (wv >> 1) << 6;

    const unsigned short* wl = wt + (size_t)lab * (LEGO * KDIM);
    const unsigned short* arow[4];
#pragma unroll
    for (int mi = 0; mi < 4; ++mi)
        arow[mi] = wl + (size_t)(m_base + mi*16 + l16) * KDIM + quad * 8;

    int prow[4], pcol[4];
#pragma unroll
    for (int ni = 0; ni < 4; ++ni) {
        int p = n_base + ni*16 + l16;
        prow[ni] = p >> 5;
        pcol[ni] = p & 31;
    }

    f32x4 acc[4][4];
    {
        f32x4 zz = {0.f, 0.f, 0.f, 0.f};
#pragma unroll
        for (int mi = 0; mi < 4; ++mi)
#pragma unroll
            for (int ni = 0; ni < 4; ++ni) acc[mi][ni] = zz;
    }

    // ---- software-pipelined main loop ----------------------------------
    // A address is linear in step (kb = step*32). Prefetch distance 2 via a
    // 3-bank register ring: loads for step s+2 are in flight during the 16
    // MFMAs of step s (~150 issue cycles) -> L2 latency hidden.
    s16x8 ap[3][4];
#pragma unroll
    for (int s = 0; s < 2; ++s)
#pragma unroll
        for (int mi = 0; mi < 4; ++mi)
            ap[s][mi] = *(const s16x8*)(arow[mi] + s * 32);

#pragma unroll
    for (int off = 0; off < 9; ++off) {
        const int dh = off / 3 - 1;
        const int dw = off % 3 - 1;
        int bbase[4], bsw[4];
#pragma unroll
        for (int ni = 0; ni < 4; ++ni) {
            int row = prow[ni] + dh + 1;      // 0..5, always staged
            int w1  = pcol[ni] + dw + 1;      // 0..33, borders are zeros
            bbase[ni] = (row * WPITCH + w1) * 128;
            bsw[ni]   = w1 & 15;
        }
#pragma unroll
        for (int kc = 0; kc < 4; ++kc) {
            const int step = off * 4 + kc;
            if (step + 2 < 36) {              // prefetch A for step+2
#pragma unroll
                for (int mi = 0; mi < 4; ++mi)
                    ap[(step + 2) % 3][mi] = *(const s16x8*)(arow[mi] + (step + 2) * 32);
            }
            const int jj = kc * 4 + quad;
            s16x8 bb[4];
#pragma unroll
            for (int ni = 0; ni < 4; ++ni)
                bb[ni] = *(const s16x8*)(xl + bbase[ni] + ((jj ^ bsw[ni]) << 3)); // ds_read_b128
            const s16x8* a = ap[step % 3];
#pragma unroll
            for (int mi = 0; mi < 4; ++mi)
#pragma unroll
                for (int ni = 0; ni < 4; ++ni)
                    acc[mi][ni] = __builtin_amdgcn_mfma_f32_16x16x32_bf16(a[mi], bb[ni], acc[mi][ni], 0, 0, 0);
        }
    }

    __syncthreads();                          // all LDS x reads done; reuse as feat
    unsigned short* featb = xl;               // feat bf16 [128][132] (pad breaks quad collisions)
#pragma unroll
    for (int mi = 0; mi < 4; ++mi)
#pragma unroll
        for (int ni = 0; ni < 4; ++ni) {
            int n = n_base + ni*16 + l16;
#pragma unroll
            for (int r = 0; r < 4; ++r) {
                int m = m_base + mi*16 + quad*4 + r;   // m89-verified C/D layout
                featb[m * 132 + n] = f2bf(acc[mi][ni][r]);
            }
        }
    __syncthreads();

    // out[b][o][nt*128 + p] = c[o] * feat[sel[o]][p]; sel/cs are 2 KB, L2-hot
    const size_t obase = ((size_t)b * OUTC) * 1024 + (size_t)nt * 128;
    for (int i = t; i < OUTC * 32; i += 256) {
        int pg = i & 31;
        int o  = i >> 5;
        int so = sel[o];
        float cc = cs[o];
        s16x4 fv = *(const s16x4*)(featb + so * 132 + pg * 4);
        f32x4 ov;
#pragma unroll
        for (int j = 0; j < 4; ++j)
            ov[j] = cc * bf2f((unsigned short)fv[j]);
        __builtin_nontemporal_store(ov, (f32x4*)(out + obase + (size_t)o * 1024 + pg * 4));
    }
}

extern "C" void kernel_launch(void* const* d_in, const int* in_sizes, int n_in,
                              void* d_out, int out_size, void* d_ws, size_t ws_size,
                              hipStream_t stream) {
    const float* x     = (const float*)d_in[0];
    const int*   label = (const int*)d_in[1];
    const float* ff    = (const float*)d_in[2];
    const float* coeff = (const float*)d_in[3];   // second_filter_coefficients (use [0] slice)
    const float* comb  = (const float*)d_in[4];   // second_filter_combination  (use [0] slice)
    float* out = (float*)d_out;

    char* ws = (char*)d_ws;
    unsigned short* wt = (unsigned short*)ws;               // 10*128*1152*2 = 2,949,120 B
    int*   sel = (int*)(ws + 2949120);                      // 2 KB
    float* cs  = (float*)(ws + 2949120 + 2048);             // 2 KB

    k_prep_w  <<<640, 256, 0, stream>>>(ff, wt);
    k_prep_sel<<<2,   256, 0, stream>>>(coeff, comb, sel, cs);
    k_conv    <<<dim3(8, 128), 256, 0, stream>>>(x, label, wt, sel, cs, out);
}